// Round 1
// baseline (157.784 us; speedup 1.0000x reference)
//
#include <hip/hip_runtime.h>

constexpr float ALPHA = 0.001f;
constexpr float BETA  = 0.001f;
constexpr int R   = 64;
constexpr int S   = 3;
constexpr int PFW = R * (1 + 2 * S); // 448 floats per pF row

// 16 lanes cooperate on one b; each wave handles 4 b's.
__global__ __launch_bounds__(256) void mf_if_kernel(
    const float* __restrict__ pF,
    const float* __restrict__ M,
    const int*   __restrict__ ijk,
    float* __restrict__ out,
    int B)
{
    const int lane = threadIdx.x & 63;
    const int sub  = lane & 15;   // lane within 16-lane group
    const int grp  = lane >> 4;   // which of 4 groups in the wave
    const long wave = (long)(blockIdx.x) * (blockDim.x >> 6) + (threadIdx.x >> 6);
    const long b = wave * 4 + grp;
    if (b >= B) return;

    const int i  = ijk[3 * b + 0];
    const int j  = ijk[3 * b + 1];
    const int k  = ijk[3 * b + 2];
    const int kc = (k < 0) ? 0 : k;

    const float4* pFi = reinterpret_cast<const float4*>(pF + (size_t)i * PFW);
    const float4* Mjp = reinterpret_cast<const float4*>(M + (size_t)j  * R);
    const float4* Mkp = reinterpret_cast<const float4*>(M + (size_t)kc * R);

    const float4 mj = Mjp[sub];
    const float4 mk = Mkp[sub];
    const float4 pi = pFi[sub];                 // Pi[4*sub .. 4*sub+3]

    float p = pi.x * mj.x + pi.y * mj.y + pi.z * mj.z + pi.w * mj.w;

    // Vs block: floats [R + sub*12, +12)  -> float4 idx 16 + 3*sub + {0,1,2}
    // flat index f = q*3 + s over the 12 floats (q = local row 0..3, s = 0..2)
    const float4 v0 = pFi[16 + 3 * sub + 0];
    const float4 v1 = pFi[16 + 3 * sub + 1];
    const float4 v2 = pFi[16 + 3 * sub + 2];
    float a0 = v0.x * mj.x + v0.w * mj.y + v1.z * mj.z + v2.y * mj.w;
    float a1 = v0.y * mj.x + v1.x * mj.y + v1.w * mj.z + v2.z * mj.w;
    float a2 = v0.z * mj.x + v1.y * mj.y + v2.x * mj.z + v2.w * mj.w;

    // Vg block: floats [(1+S)*R + sub*12, +12) -> float4 idx 64 + 3*sub + {0,1,2}
    const float4 w0 = pFi[64 + 3 * sub + 0];
    const float4 w1 = pFi[64 + 3 * sub + 1];
    const float4 w2 = pFi[64 + 3 * sub + 2];
    float g0 = w0.x * mk.x + w0.w * mk.y + w1.z * mk.z + w2.y * mk.w;
    float g1 = w0.y * mk.x + w1.x * mk.y + w1.w * mk.z + w2.z * mk.w;
    float g2 = w0.z * mk.x + w1.y * mk.y + w2.x * mk.z + w2.w * mk.w;

    // Reduce the 7 partials across the 16-lane group (xor offsets stay in-group).
    #pragma unroll
    for (int off = 8; off >= 1; off >>= 1) {
        p  += __shfl_xor(p,  off);
        a0 += __shfl_xor(a0, off);
        a1 += __shfl_xor(a1, off);
        a2 += __shfl_xor(a2, off);
        g0 += __shfl_xor(g0, off);
        g1 += __shfl_xor(g1, off);
        g2 += __shfl_xor(g2, off);
    }

    if (sub == 0) {
        // Both a and g each carry one factor of BETA in the reference;
        // fold BETA*BETA in at the end instead of scaling 384 elements.
        const float mfm = (k != -1)
            ? (BETA * BETA) * (a0 * g0 + a1 * g1 + a2 * g2)
            : 0.0f;
        out[b] = ALPHA * p + mfm;
    }
}

extern "C" void kernel_launch(void* const* d_in, const int* in_sizes, int n_in,
                              void* d_out, int out_size, void* d_ws, size_t ws_size,
                              hipStream_t stream) {
    const float* pF  = (const float*)d_in[0];
    const float* M   = (const float*)d_in[1];
    const int*   ijk = (const int*)d_in[2];
    float* out = (float*)d_out;

    const int B = in_sizes[2] / 3;          // 500000
    const long total_threads = (long)B * 16; // 16 lanes per b
    const int threads = 256;
    const int blocks = (int)((total_threads + threads - 1) / threads);

    mf_if_kernel<<<blocks, threads, 0, stream>>>(pF, M, ijk, out, B);
}